// Round 4
// baseline (225.600 us; speedup 1.0000x reference)
//
#include <hip/hip_runtime.h>
#include <math.h>

#define BATCH 4096
#define DIM 128
#define NCLS 100
#define MARGIN 0.3f
#define GRID_MAIN 1280

typedef __attribute__((ext_vector_type(8))) short short8;
typedef __attribute__((ext_vector_type(4))) float f32x4;

// ---- bf16 helpers (bit-level, RNE) ----
__device__ __forceinline__ unsigned short f2bf(float f) {
    unsigned int u = __float_as_uint(f);
    unsigned int r = (u + 0x7FFFu + ((u >> 16) & 1u)) >> 16;
    return (unsigned short)r;
}
__device__ __forceinline__ float bf2f(unsigned short b) {
    return __uint_as_float(((unsigned int)b) << 16);
}

// K1: blocks 0..255: convert emb->bf16 + sq (from rounded values, so diag d2==0).
//     blocks 256..257: convert fc_w -> bf16 wbf[112][128] (padded); zero ticket.
__global__ __launch_bounds__(256) void prep_kernel(
        const float* __restrict__ emb, const float* __restrict__ fcw,
        unsigned short* __restrict__ ebf, float* __restrict__ sq,
        unsigned short* __restrict__ wbf, int* __restrict__ ticket) {
    int bid = blockIdx.x, tid = threadIdx.x;
    if (bid < 256) {
        int wave = tid >> 6, lane = tid & 63;
        #pragma unroll
        for (int r = 0; r < 4; ++r) {
            int row = bid * 16 + wave * 4 + r;
            const float2* src = reinterpret_cast<const float2*>(emb + row * DIM);
            float2 xy = src[lane];
            unsigned short b0 = f2bf(xy.x), b1 = f2bf(xy.y);
            float y0 = bf2f(b0), y1 = bf2f(b1);
            reinterpret_cast<unsigned int*>(ebf + row * DIM)[lane] =
                ((unsigned int)b1 << 16) | (unsigned int)b0;
            float acc = y0 * y0 + y1 * y1;
            #pragma unroll
            for (int off = 1; off < 64; off <<= 1) acc += __shfl_xor(acc, off, 64);
            if (lane == 0) sq[row] = acc;
        }
    } else {
        if (bid == 256 && tid == 0) *ticket = 0;
        int idx = (bid - 256) * 256 + tid;          // 512 threads total
        for (int k = idx; k < 112 * DIM; k += 512) {
            wbf[k] = (k < NCLS * DIM) ? f2bf(fcw[k]) : (unsigned short)0;
        }
    }
}

// K2 (fused): blocks 0..1023   -> pairwise hardest-pos/neg partials (16 col-chunks)
//             blocks 1024..1279 -> CE per 16 rows via MFMA logits + wave softmax
//             last-finishing block (ticket fan-in) -> final reduce, writes out[0].
__global__ __launch_bounds__(256) void main_kernel(
        const unsigned short* __restrict__ ebf, const unsigned short* __restrict__ wbf,
        const float* __restrict__ sq, const int* __restrict__ labels,
        const float* __restrict__ fcb,
        float* __restrict__ appart, float* __restrict__ anpart,
        float* __restrict__ ce, int* __restrict__ ticket,
        float* __restrict__ out) {
    __shared__ float lg[16][128];
    __shared__ int lastFlag;
    int bid = blockIdx.x, tid = threadIdx.x;
    int wave = tid >> 6, lane = tid & 63;
    int lm = lane & 15, lq = lane >> 4;
    int koff = lq * 8;                 // frag: [idx=lane&15][k = lq*8 + j], 4 k-steps of 32

    if (bid < 1024) {
        // ---------------- pairwise ----------------
        int rowgrp = bid >> 4, chunk = bid & 15;
        int rbase = rowgrp * 64 + wave * 16;
        int arow = rbase + lm;
        const unsigned short* apt = ebf + arow * DIM + koff;
        short8 a0 = *reinterpret_cast<const short8*>(apt);
        short8 a1 = *reinterpret_cast<const short8*>(apt + 32);
        short8 a2 = *reinterpret_cast<const short8*>(apt + 64);
        short8 a3 = *reinterpret_cast<const short8*>(apt + 96);

        int labr[4];
        #pragma unroll
        for (int r = 0; r < 4; ++r) labr[r] = labels[rbase + lq * 4 + r];

        float rmax[4] = {-INFINITY, -INFINITY, -INFINITY, -INFINITY};
        float rmin[4] = { INFINITY,  INFINITY,  INFINITY,  INFINITY};

        int cbase = chunk * 256;
        #pragma unroll 4
        for (int ct = 0; ct < 16; ++ct) {
            int col = cbase + ct * 16 + lm;
            const unsigned short* bp = ebf + col * DIM + koff;
            short8 b0 = *reinterpret_cast<const short8*>(bp);
            short8 b1 = *reinterpret_cast<const short8*>(bp + 32);
            short8 b2 = *reinterpret_cast<const short8*>(bp + 64);
            short8 b3 = *reinterpret_cast<const short8*>(bp + 96);
            f32x4 c = {0.f, 0.f, 0.f, 0.f};
            c = __builtin_amdgcn_mfma_f32_16x16x32_bf16(a0, b0, c, 0, 0, 0);
            c = __builtin_amdgcn_mfma_f32_16x16x32_bf16(a1, b1, c, 0, 0, 0);
            c = __builtin_amdgcn_mfma_f32_16x16x32_bf16(a2, b2, c, 0, 0, 0);
            c = __builtin_amdgcn_mfma_f32_16x16x32_bf16(a3, b3, c, 0, 0, 0);
            float sqc = sq[col];
            int lc = labels[col];
            #pragma unroll
            for (int r = 0; r < 4; ++r) {
                float v = fmaf(c[r], -2.0f, sqc);     // sq_j - 2*dot (sq_i added later)
                bool same = (lc == labr[r]);
                rmax[r] = same ? fmaxf(rmax[r], v) : rmax[r];
                rmin[r] = same ? rmin[r] : fminf(rmin[r], v);
            }
        }
        #pragma unroll
        for (int off = 1; off < 16; off <<= 1) {
            #pragma unroll
            for (int r = 0; r < 4; ++r) {
                rmax[r] = fmaxf(rmax[r], __shfl_xor(rmax[r], off, 64));
                rmin[r] = fminf(rmin[r], __shfl_xor(rmin[r], off, 64));
            }
        }
        if (lm == 0) {
            int row0 = rbase + lq * 4;
            #pragma unroll
            for (int r = 0; r < 4; ++r) {
                appart[(row0 + r) * 16 + chunk] = rmax[r];
                anpart[(row0 + r) * 16 + chunk] = rmin[r];
            }
        }
    } else {
        // ---------------- cross-entropy ----------------
        int R0 = (bid - 1024) * 16;
        lg[tid >> 4][112 + (tid & 15)] = -INFINITY;   // pad cols 112..127

        int arow = R0 + lm;
        const unsigned short* apt = ebf + arow * DIM + koff;
        short8 a0 = *reinterpret_cast<const short8*>(apt);
        short8 a1 = *reinterpret_cast<const short8*>(apt + 32);
        short8 a2 = *reinterpret_cast<const short8*>(apt + 64);
        short8 a3 = *reinterpret_cast<const short8*>(apt + 96);

        for (int t = wave * 2; t < 7 && t < wave * 2 + 2; ++t) {
            int cls = t * 16 + lm;
            const unsigned short* bp = wbf + cls * DIM + koff;
            short8 b0 = *reinterpret_cast<const short8*>(bp);
            short8 b1 = *reinterpret_cast<const short8*>(bp + 32);
            short8 b2 = *reinterpret_cast<const short8*>(bp + 64);
            short8 b3 = *reinterpret_cast<const short8*>(bp + 96);
            f32x4 c = {0.f, 0.f, 0.f, 0.f};
            c = __builtin_amdgcn_mfma_f32_16x16x32_bf16(a0, b0, c, 0, 0, 0);
            c = __builtin_amdgcn_mfma_f32_16x16x32_bf16(a1, b1, c, 0, 0, 0);
            c = __builtin_amdgcn_mfma_f32_16x16x32_bf16(a2, b2, c, 0, 0, 0);
            c = __builtin_amdgcn_mfma_f32_16x16x32_bf16(a3, b3, c, 0, 0, 0);
            float bias = (cls < NCLS) ? fcb[cls] : -INFINITY;
            #pragma unroll
            for (int r = 0; r < 4; ++r)
                lg[lq * 4 + r][t * 16 + lm] = c[r] + bias;
        }
        __syncthreads();
        #pragma unroll
        for (int i = 0; i < 4; ++i) {
            int r = wave * 4 + i;
            float x0 = lg[r][lane], x1 = lg[r][lane + 64];
            float m = fmaxf(x0, x1);
            #pragma unroll
            for (int off = 1; off < 64; off <<= 1) m = fmaxf(m, __shfl_xor(m, off, 64));
            float s = expf(x0 - m) + expf(x1 - m);    // -inf pads -> 0
            #pragma unroll
            for (int off = 1; off < 64; off <<= 1) s += __shfl_xor(s, off, 64);
            if (lane == 0) {
                int lab = labels[R0 + r];
                ce[R0 + r] = (m + logf(s)) - lg[r][lab];
            }
        }
    }

    // ---------------- ticket fan-in: last block does the final reduce ----------------
    __threadfence();                        // publish this block's partials (device scope)
    __syncthreads();
    if (tid == 0) lastFlag = (atomicAdd(ticket, 1) == GRID_MAIN - 1);
    __syncthreads();
    if (lastFlag) {
        __threadfence();                    // acquire: see all other blocks' partials
        float acc = 0.f;
        #pragma unroll
        for (int rr = 0; rr < 16; ++rr) {
            int row = rr * 256 + tid;
            const float4* ap = reinterpret_cast<const float4*>(appart + row * 16);
            const float4* an = reinterpret_cast<const float4*>(anpart + row * 16);
            float m = -INFINITY, n = INFINITY;
            #pragma unroll
            for (int p = 0; p < 4; ++p) {
                float4 a = ap[p];
                m = fmaxf(m, fmaxf(fmaxf(a.x, a.y), fmaxf(a.z, a.w)));
                float4 b = an[p];
                n = fminf(n, fminf(fminf(b.x, b.y), fminf(b.z, b.w)));
            }
            float api = sqrtf(fmaxf(sq[row] + m, 1e-12f));
            float ani = sqrtf(fmaxf(sq[row] + n, 1e-12f));
            acc += fmaxf(api - ani + MARGIN, 0.f) + ce[row];
        }
        float* red = reinterpret_cast<float*>(lg);
        red[tid] = acc;
        __syncthreads();
        for (int s = 128; s > 0; s >>= 1) {
            if (tid < s) red[tid] += red[tid + s];
            __syncthreads();
        }
        if (tid == 0) out[0] = red[0] * (1.0f / BATCH);   // single writer, no memset needed
    }
}

extern "C" void kernel_launch(void* const* d_in, const int* in_sizes, int n_in,
                              void* d_out, int out_size, void* d_ws, size_t ws_size,
                              hipStream_t stream) {
    const float* emb    = (const float*)d_in[0];
    const int*   labels = (const int*)  d_in[1];
    const float* fcw    = (const float*)d_in[2];
    const float* fcb    = (const float*)d_in[3];
    float* out = (float*)d_out;

    char* ws = (char*)d_ws;
    unsigned short* ebf = (unsigned short*)(ws);                 // 1 MB
    unsigned short* wbf = (unsigned short*)(ws + 1048576);       // 28 KB (pad to 32K)
    float* sq     = (float*)(ws + 1081344);                      // 16 KB
    float* ce     = (float*)(ws + 1097728);                      // 16 KB
    float* appart = (float*)(ws + 1114112);                      // 256 KB
    float* anpart = (float*)(ws + 1376256);                      // 256 KB
    int*   ticket = (int*)  (ws + 1638400);                      // 4 B

    prep_kernel<<<258, 256, 0, stream>>>(emb, fcw, ebf, sq, wbf, ticket);
    main_kernel<<<GRID_MAIN, 256, 0, stream>>>(ebf, wbf, sq, labels, fcb,
                                               appart, anpart, ce, ticket, out);
}

// Round 5
// 118.564 us; speedup vs baseline: 1.9028x; 1.9028x over previous
//
#include <hip/hip_runtime.h>
#include <math.h>

#define BATCH 4096
#define DIM 128
#define NCLS 100
#define MARGIN 0.3f
#define GRID_MAIN 1280

typedef __attribute__((ext_vector_type(8))) short short8;
typedef __attribute__((ext_vector_type(4))) float f32x4;

// ---- bf16 helpers (bit-level, RNE) ----
__device__ __forceinline__ unsigned short f2bf(float f) {
    unsigned int u = __float_as_uint(f);
    unsigned int r = (u + 0x7FFFu + ((u >> 16) & 1u)) >> 16;
    return (unsigned short)r;
}
__device__ __forceinline__ float bf2f(unsigned short b) {
    return __uint_as_float(((unsigned int)b) << 16);
}

// Order-preserving encodings for NONNEGATIVE floats, identity = 0 for atomicMax.
// enc_max: bigger v -> bigger key; all keys >= 0x80000000 > 0-init.
// enc_min: bigger v -> SMALLER key (atomicMax selects min v); keys in (0,0x7FFFFFFF].
__device__ __forceinline__ unsigned int enc_max(float v) {
    return (__float_as_uint(v) >> 1) | 0x80000000u;
}
__device__ __forceinline__ float dec_max(unsigned int k) {
    return __uint_as_float((k & 0x7FFFFFFFu) << 1);
}
__device__ __forceinline__ unsigned int enc_min(float v) {
    return 0x7FFFFFFFu - (__float_as_uint(v) >> 1);
}
__device__ __forceinline__ float dec_min(unsigned int k) {
    return __uint_as_float((0x7FFFFFFFu - k) << 1);
}

// K1: blocks 0..255: convert emb->bf16 + sq (from rounded values, so diag d2==0).
//     blocks 256..257: convert fc_w -> bf16 wbf[112][128] (padded classes zeroed).
__global__ __launch_bounds__(256) void prep_kernel(
        const float* __restrict__ emb, const float* __restrict__ fcw,
        unsigned short* __restrict__ ebf, float* __restrict__ sq,
        unsigned short* __restrict__ wbf) {
    int bid = blockIdx.x, tid = threadIdx.x;
    if (bid < 256) {
        int wave = tid >> 6, lane = tid & 63;
        #pragma unroll
        for (int r = 0; r < 4; ++r) {
            int row = bid * 16 + wave * 4 + r;
            const float2* src = reinterpret_cast<const float2*>(emb + row * DIM);
            float2 xy = src[lane];
            unsigned short b0 = f2bf(xy.x), b1 = f2bf(xy.y);
            float y0 = bf2f(b0), y1 = bf2f(b1);
            reinterpret_cast<unsigned int*>(ebf + row * DIM)[lane] =
                ((unsigned int)b1 << 16) | (unsigned int)b0;
            float acc = y0 * y0 + y1 * y1;
            #pragma unroll
            for (int off = 1; off < 64; off <<= 1) acc += __shfl_xor(acc, off, 64);
            if (lane == 0) sq[row] = acc;
        }
    } else {
        int idx = (bid - 256) * 256 + tid;          // 512 threads total
        for (int k = idx; k < 112 * DIM; k += 512) {
            wbf[k] = (k < NCLS * DIM) ? f2bf(fcw[k]) : (unsigned short)0;
        }
    }
}

// K2: blocks 0..1023   -> pairwise; hardest-pos/neg fan-in via device-scope
//                         atomicMax on encoded d^2 (no fences!).
//     blocks 1024..1279 -> CE per 16 rows; one atomicAdd(ce_sum) per block.
//     ticket fan-in (relaxed atomics + s_waitcnt vmcnt(0)); last block reduces.
__global__ __launch_bounds__(256) void main_kernel(
        const unsigned short* __restrict__ ebf, const unsigned short* __restrict__ wbf,
        const float* __restrict__ sq, const int* __restrict__ labels,
        const float* __restrict__ fcb,
        unsigned int* __restrict__ maxk, unsigned int* __restrict__ mink,
        float* __restrict__ ce_sum, int* __restrict__ ticket,
        float* __restrict__ out) {
    __shared__ float lg[16][128];
    __shared__ int lastFlag;
    int bid = blockIdx.x, tid = threadIdx.x;
    int wave = tid >> 6, lane = tid & 63;
    int lm = lane & 15, lq = lane >> 4;
    int koff = lq * 8;                 // frag: [idx=lane&15][k = lq*8 + j]

    if (bid < 1024) {
        // ---------------- pairwise ----------------
        int rowgrp = bid >> 4, chunk = bid & 15;
        int rbase = rowgrp * 64 + wave * 16;
        int arow = rbase + lm;
        const unsigned short* apt = ebf + arow * DIM + koff;
        short8 a0 = *reinterpret_cast<const short8*>(apt);
        short8 a1 = *reinterpret_cast<const short8*>(apt + 32);
        short8 a2 = *reinterpret_cast<const short8*>(apt + 64);
        short8 a3 = *reinterpret_cast<const short8*>(apt + 96);

        int labr[4];
        float sqr[4];
        #pragma unroll
        for (int r = 0; r < 4; ++r) {
            labr[r] = labels[rbase + lq * 4 + r];
            sqr[r]  = sq[rbase + lq * 4 + r];
        }

        float rmax[4] = {-INFINITY, -INFINITY, -INFINITY, -INFINITY};
        float rmin[4] = { INFINITY,  INFINITY,  INFINITY,  INFINITY};

        int cbase = chunk * 256;
        #pragma unroll 4
        for (int ct = 0; ct < 16; ++ct) {
            int col = cbase + ct * 16 + lm;
            const unsigned short* bp = ebf + col * DIM + koff;
            short8 b0 = *reinterpret_cast<const short8*>(bp);
            short8 b1 = *reinterpret_cast<const short8*>(bp + 32);
            short8 b2 = *reinterpret_cast<const short8*>(bp + 64);
            short8 b3 = *reinterpret_cast<const short8*>(bp + 96);
            f32x4 c = {0.f, 0.f, 0.f, 0.f};
            c = __builtin_amdgcn_mfma_f32_16x16x32_bf16(a0, b0, c, 0, 0, 0);
            c = __builtin_amdgcn_mfma_f32_16x16x32_bf16(a1, b1, c, 0, 0, 0);
            c = __builtin_amdgcn_mfma_f32_16x16x32_bf16(a2, b2, c, 0, 0, 0);
            c = __builtin_amdgcn_mfma_f32_16x16x32_bf16(a3, b3, c, 0, 0, 0);
            float sqc = sq[col];
            int lc = labels[col];
            #pragma unroll
            for (int r = 0; r < 4; ++r) {
                float v = fmaf(c[r], -2.0f, sqc) + sqr[r];   // full d^2
                bool same = (lc == labr[r]);
                rmax[r] = same ? fmaxf(rmax[r], v) : rmax[r];
                rmin[r] = same ? rmin[r] : fminf(rmin[r], v);
            }
        }
        #pragma unroll
        for (int off = 1; off < 16; off <<= 1) {
            #pragma unroll
            for (int r = 0; r < 4; ++r) {
                rmax[r] = fmaxf(rmax[r], __shfl_xor(rmax[r], off, 64));
                rmin[r] = fminf(rmin[r], __shfl_xor(rmin[r], off, 64));
            }
        }
        if (lm == 0) {
            int row0 = rbase + lq * 4;
            #pragma unroll
            for (int r = 0; r < 4; ++r) {
                // clamp tiny negatives (bf16/fp32 rounding) so encodings are valid
                unsigned int kx = enc_max(fmaxf(rmax[r], 0.f));
                unsigned int kn = enc_min(fmaxf(rmin[r], 0.f));
                __hip_atomic_fetch_max(&maxk[row0 + r], kx,
                                       __ATOMIC_RELAXED, __HIP_MEMORY_SCOPE_AGENT);
                __hip_atomic_fetch_max(&mink[row0 + r], kn,
                                       __ATOMIC_RELAXED, __HIP_MEMORY_SCOPE_AGENT);
            }
        }
    } else {
        // ---------------- cross-entropy ----------------
        int R0 = (bid - 1024) * 16;
        lg[tid >> 4][112 + (tid & 15)] = -INFINITY;   // pad cols 112..127

        int arow = R0 + lm;
        const unsigned short* apt = ebf + arow * DIM + koff;
        short8 a0 = *reinterpret_cast<const short8*>(apt);
        short8 a1 = *reinterpret_cast<const short8*>(apt + 32);
        short8 a2 = *reinterpret_cast<const short8*>(apt + 64);
        short8 a3 = *reinterpret_cast<const short8*>(apt + 96);

        for (int t = wave * 2; t < 7 && t < wave * 2 + 2; ++t) {
            int cls = t * 16 + lm;
            const unsigned short* bp = wbf + cls * DIM + koff;
            short8 b0 = *reinterpret_cast<const short8*>(bp);
            short8 b1 = *reinterpret_cast<const short8*>(bp + 32);
            short8 b2 = *reinterpret_cast<const short8*>(bp + 64);
            short8 b3 = *reinterpret_cast<const short8*>(bp + 96);
            f32x4 c = {0.f, 0.f, 0.f, 0.f};
            c = __builtin_amdgcn_mfma_f32_16x16x32_bf16(a0, b0, c, 0, 0, 0);
            c = __builtin_amdgcn_mfma_f32_16x16x32_bf16(a1, b1, c, 0, 0, 0);
            c = __builtin_amdgcn_mfma_f32_16x16x32_bf16(a2, b2, c, 0, 0, 0);
            c = __builtin_amdgcn_mfma_f32_16x16x32_bf16(a3, b3, c, 0, 0, 0);
            float bias = (cls < NCLS) ? fcb[cls] : -INFINITY;
            #pragma unroll
            for (int r = 0; r < 4; ++r)
                lg[lq * 4 + r][t * 16 + lm] = c[r] + bias;
        }
        __syncthreads();
        float cacc = 0.f;
        #pragma unroll
        for (int i = 0; i < 4; ++i) {
            int r = wave * 4 + i;
            float x0 = lg[r][lane], x1 = lg[r][lane + 64];
            float m = fmaxf(x0, x1);
            #pragma unroll
            for (int off = 1; off < 64; off <<= 1) m = fmaxf(m, __shfl_xor(m, off, 64));
            float s = expf(x0 - m) + expf(x1 - m);    // -inf pads -> 0
            #pragma unroll
            for (int off = 1; off < 64; off <<= 1) s += __shfl_xor(s, off, 64);
            if (lane == 0) {
                int lab = labels[R0 + r];
                cacc += (m + logf(s)) - lg[r][lab];
            }
        }
        __syncthreads();          // lg reuse below
        if (lane == 0) lg[0][wave] = cacc;
        __syncthreads();
        if (tid == 0) {
            float bsum = lg[0][0] + lg[0][1] + lg[0][2] + lg[0][3];
            __hip_atomic_fetch_add(ce_sum, bsum,
                                   __ATOMIC_RELAXED, __HIP_MEMORY_SCOPE_AGENT);
        }
    }

    // ------- fence-free ticket fan-in: drain this wave's atomics, then count -------
    __syncthreads();
    asm volatile("s_waitcnt vmcnt(0)" ::: "memory");
    if (tid == 0) {
        int old = __hip_atomic_fetch_add(ticket, 1,
                                         __ATOMIC_RELAXED, __HIP_MEMORY_SCOPE_AGENT);
        lastFlag = (old == GRID_MAIN - 1);
    }
    __syncthreads();
    if (lastFlag) {
        float acc = 0.f;
        #pragma unroll
        for (int rr = 0; rr < 16; ++rr) {
            int row = rr * 256 + tid;
            unsigned int kx = __hip_atomic_load(&maxk[row], __ATOMIC_RELAXED,
                                                __HIP_MEMORY_SCOPE_AGENT);
            unsigned int kn = __hip_atomic_load(&mink[row], __ATOMIC_RELAXED,
                                                __HIP_MEMORY_SCOPE_AGENT);
            float ap = sqrtf(fmaxf(dec_max(kx), 1e-12f));
            float an = sqrtf(fmaxf(dec_min(kn), 1e-12f));
            acc += fmaxf(ap - an + MARGIN, 0.f);
        }
        float* red = reinterpret_cast<float*>(lg);
        red[tid] = acc;
        __syncthreads();
        for (int s = 128; s > 0; s >>= 1) {
            if (tid < s) red[tid] += red[tid + s];
            __syncthreads();
        }
        if (tid == 0) {
            float ces = __hip_atomic_load(ce_sum, __ATOMIC_RELAXED,
                                          __HIP_MEMORY_SCOPE_AGENT);
            out[0] = (red[0] + ces) * (1.0f / BATCH);
        }
    }
}

extern "C" void kernel_launch(void* const* d_in, const int* in_sizes, int n_in,
                              void* d_out, int out_size, void* d_ws, size_t ws_size,
                              hipStream_t stream) {
    const float* emb    = (const float*)d_in[0];
    const int*   labels = (const int*)  d_in[1];
    const float* fcw    = (const float*)d_in[2];
    const float* fcb    = (const float*)d_in[3];
    float* out = (float*)d_out;

    char* ws = (char*)d_ws;
    unsigned short* ebf = (unsigned short*)(ws);                 // 1 MB
    unsigned short* wbf = (unsigned short*)(ws + 1048576);       // 28 KB (pad 32K)
    float* sq           = (float*)(ws + 1081344);                // 16 KB
    // fan-in region: ONE memset(0) initializes everything (0 = identity for
    // both encodings, exact zero for ce_sum, zero ticket).
    char* fan           = ws + 1097728;
    int*   ticket       = (int*)(fan);                           // 4 B
    float* ce_sum       = (float*)(fan + 4);                     // 4 B
    unsigned int* maxk  = (unsigned int*)(fan + 8);              // 16 KB
    unsigned int* mink  = (unsigned int*)(fan + 8 + 16384);      // 16 KB

    hipMemsetAsync(fan, 0, 8 + 32768, stream);
    prep_kernel<<<258, 256, 0, stream>>>(emb, fcw, ebf, sq, wbf);
    main_kernel<<<GRID_MAIN, 256, 0, stream>>>(ebf, wbf, sq, labels, fcb,
                                               maxk, mink, ce_sum, ticket, out);
}

// Round 7
// 101.466 us; speedup vs baseline: 2.2234x; 1.1685x over previous
//
#include <hip/hip_runtime.h>
#include <math.h>

#define BATCH 4096
#define DIM 128
#define NCLS 100
#define MARGIN 0.3f
#define NTILE 544          // upper-triangle 64x256 tiles
#define GRID_MAIN 800      // 544 pairwise + 256 CE

typedef __attribute__((ext_vector_type(8))) short short8;
typedef __attribute__((ext_vector_type(4))) float f32x4;

// ---- bf16 helpers (bit-level, RNE) ----
__device__ __forceinline__ unsigned short f2bf(float f) {
    unsigned int u = __float_as_uint(f);
    unsigned int r = (u + 0x7FFFu + ((u >> 16) & 1u)) >> 16;
    return (unsigned short)r;
}
__device__ __forceinline__ float bf2f(unsigned short b) {
    return __uint_as_float(((unsigned int)b) << 16);
}

// Order-preserving encodings for NONNEGATIVE floats; identity = 0 under atomic max.
// enc_max: bigger v -> bigger key (keys >= 0x80000000).
// enc_min: bigger v -> smaller key (atomic max selects min v).
#define ENC_MAX_ID 0x80000000u   /* enc_max(0.0f) */
#define ENC_MIN_ID 0x403FFFFFu   /* enc_min(+inf) */
__device__ __forceinline__ unsigned int enc_max(float v) {
    return (__float_as_uint(v) >> 1) | 0x80000000u;
}
__device__ __forceinline__ float dec_max(unsigned int k) {
    return __uint_as_float((k & 0x7FFFFFFFu) << 1);
}
__device__ __forceinline__ unsigned int enc_min(float v) {
    return 0x7FFFFFFFu - (__float_as_uint(v) >> 1);
}
__device__ __forceinline__ float dec_min(unsigned int k) {
    return __uint_as_float((0x7FFFFFFFu - k) << 1);
}

// K1: blocks 0..255: emb->bf16 + sq (from rounded values so diag d2==0).
//     blocks 256..257: fc_w->bf16 (padded to 112 classes) + zero fan-in region.
__global__ __launch_bounds__(256) void prep_kernel(
        const float* __restrict__ emb, const float* __restrict__ fcw,
        unsigned short* __restrict__ ebf, float* __restrict__ sq,
        unsigned short* __restrict__ wbf, unsigned int* __restrict__ fanz) {
    int bid = blockIdx.x, tid = threadIdx.x;
    if (bid < 256) {
        int wave = tid >> 6, lane = tid & 63;
        #pragma unroll
        for (int r = 0; r < 4; ++r) {
            int row = bid * 16 + wave * 4 + r;
            const float2* src = reinterpret_cast<const float2*>(emb + row * DIM);
            float2 xy = src[lane];
            unsigned short b0 = f2bf(xy.x), b1 = f2bf(xy.y);
            float y0 = bf2f(b0), y1 = bf2f(b1);
            reinterpret_cast<unsigned int*>(ebf + row * DIM)[lane] =
                ((unsigned int)b1 << 16) | (unsigned int)b0;
            float acc = y0 * y0 + y1 * y1;
            #pragma unroll
            for (int off = 1; off < 64; off <<= 1) acc += __shfl_xor(acc, off, 64);
            if (lane == 0) sq[row] = acc;
        }
    } else {
        int idx = (bid - 256) * 256 + tid;          // 512 threads total
        for (int k = idx; k < 112 * DIM; k += 512)
            wbf[k] = (k < NCLS * DIM) ? f2bf(fcw[k]) : (unsigned short)0;
        for (int w = idx; w < 8194; w += 512)       // ticket+ce_sum+maxk+mink
            fanz[w] = 0;
    }
}

// K2: blocks 0..543  -> upper-triangle pairwise tiles (64 rows x 256 cols);
//                       fold d^2 into ROW max/min (regs) AND COL max/min (LDS),
//                       publish via device-scope encoded atomic-max (no fences).
//     blocks 544..799 -> CE per 16 rows via MFMA logits + wave softmax.
//     ticket fan-in; last block decodes + reduces + writes out[0].
__global__ __launch_bounds__(256) void main_kernel(
        const unsigned short* __restrict__ ebf, const unsigned short* __restrict__ wbf,
        const float* __restrict__ sq, const int* __restrict__ labels,
        const float* __restrict__ fcb,
        unsigned int* __restrict__ maxk, unsigned int* __restrict__ mink,
        float* __restrict__ ce_sum, int* __restrict__ ticket,
        float* __restrict__ out) {
    __shared__ float lg[16][128];
    __shared__ unsigned int colk[512];   // [0..255] col-max keys, [256..511] col-min keys
    __shared__ int lastFlag;
    int bid = blockIdx.x, tid = threadIdx.x;
    int wave = tid >> 6, lane = tid & 63;
    int lm = lane & 15, lq = lane >> 4;
    int koff = lq * 8;                 // frag: [idx=lane&15][k = lq*8 + j]

    if (bid < NTILE) {
        // ---- map bid -> (rowgrp, chunk) in the upper triangle ----
        // R6 BUG FIX: the branchless prefix-subtract could re-fire after its
        // first failure (e.g. bid=63 landed in q=1). Plain while-loop; bid is
        // wave-uniform so this is cheap scalar control flow.
        int q = 0, rem = bid;
        while (rem >= 4 * (16 - q)) { rem -= 4 * (16 - q); ++q; }
        int cpr = 16 - q;
        int sub = rem / cpr, coff = rem % cpr;
        int rowgrp = 4 * q + sub;
        int chunk  = q + coff;

        int rbase = rowgrp * 64 + wave * 16;
        int arow = rbase + lm;
        const unsigned short* apt = ebf + arow * DIM + koff;
        short8 a0 = *reinterpret_cast<const short8*>(apt);
        short8 a1 = *reinterpret_cast<const short8*>(apt + 32);
        short8 a2 = *reinterpret_cast<const short8*>(apt + 64);
        short8 a3 = *reinterpret_cast<const short8*>(apt + 96);

        int labr[4];
        float sqr[4];
        #pragma unroll
        for (int r = 0; r < 4; ++r) {
            labr[r] = labels[rbase + lq * 4 + r];
            sqr[r]  = sq[rbase + lq * 4 + r];
        }

        colk[tid] = 0; colk[256 + tid] = 0;
        __syncthreads();

        float rmax[4] = {-INFINITY, -INFINITY, -INFINITY, -INFINITY};
        float rmin[4] = { INFINITY,  INFINITY,  INFINITY,  INFINITY};

        int cbase = chunk * 256;
        #pragma unroll 2
        for (int ct = 0; ct < 16; ++ct) {
            int col = cbase + ct * 16 + lm;
            const unsigned short* bp = ebf + col * DIM + koff;
            short8 b0 = *reinterpret_cast<const short8*>(bp);
            short8 b1 = *reinterpret_cast<const short8*>(bp + 32);
            short8 b2 = *reinterpret_cast<const short8*>(bp + 64);
            short8 b3 = *reinterpret_cast<const short8*>(bp + 96);
            f32x4 c = {0.f, 0.f, 0.f, 0.f};
            c = __builtin_amdgcn_mfma_f32_16x16x32_bf16(a0, b0, c, 0, 0, 0);
            c = __builtin_amdgcn_mfma_f32_16x16x32_bf16(a1, b1, c, 0, 0, 0);
            c = __builtin_amdgcn_mfma_f32_16x16x32_bf16(a2, b2, c, 0, 0, 0);
            c = __builtin_amdgcn_mfma_f32_16x16x32_bf16(a3, b3, c, 0, 0, 0);
            float sqc = sq[col];
            int lc = labels[col];
            float cmax = -INFINITY, cmin = INFINITY;
            #pragma unroll
            for (int r = 0; r < 4; ++r) {
                float v = fmaxf(fmaf(c[r], -2.0f, sqc) + sqr[r], 0.f);  // d^2 >= 0
                bool same = (lc == labr[r]);
                rmax[r] = same ? fmaxf(rmax[r], v) : rmax[r];
                rmin[r] = same ? rmin[r] : fminf(rmin[r], v);
                cmax    = same ? fmaxf(cmax, v) : cmax;
                cmin    = same ? cmin : fminf(cmin, v);
            }
            // fold this wave's 16 rows into the 16 cols (combine lq groups)
            cmax = fmaxf(cmax, __shfl_xor(cmax, 16, 64));
            cmax = fmaxf(cmax, __shfl_xor(cmax, 32, 64));
            cmin = fminf(cmin, __shfl_xor(cmin, 16, 64));
            cmin = fminf(cmin, __shfl_xor(cmin, 32, 64));
            if (lq == 0) {   // 16 lanes, 16 distinct banks -> conflict-free ds atomics
                atomicMax(&colk[ct * 16 + lm], enc_max(fmaxf(cmax, 0.f)));
                atomicMax(&colk[256 + ct * 16 + lm], enc_min(fmaxf(cmin, 0.f)));
            }
        }
        // row reduce across the 16 col-slots
        #pragma unroll
        for (int off = 1; off < 16; off <<= 1) {
            #pragma unroll
            for (int r = 0; r < 4; ++r) {
                rmax[r] = fmaxf(rmax[r], __shfl_xor(rmax[r], off, 64));
                rmin[r] = fminf(rmin[r], __shfl_xor(rmin[r], off, 64));
            }
        }
        if (lm == 0) {
            int row0 = rbase + lq * 4;
            #pragma unroll
            for (int r = 0; r < 4; ++r) {
                unsigned int kx = enc_max(fmaxf(rmax[r], 0.f));
                unsigned int kn = enc_min(fmaxf(rmin[r], 0.f));
                if (kx != ENC_MAX_ID)
                    __hip_atomic_fetch_max(&maxk[row0 + r], kx,
                                           __ATOMIC_RELAXED, __HIP_MEMORY_SCOPE_AGENT);
                if (kn != ENC_MIN_ID)
                    __hip_atomic_fetch_max(&mink[row0 + r], kn,
                                           __ATOMIC_RELAXED, __HIP_MEMORY_SCOPE_AGENT);
            }
        }
        __syncthreads();
        // column publish: one thread per col
        {
            unsigned int kx = colk[tid], kn = colk[256 + tid];
            int col = cbase + tid;
            if (kx > ENC_MAX_ID)       // >: skip identity AND the harmless enc_max(0)
                __hip_atomic_fetch_max(&maxk[col], kx,
                                       __ATOMIC_RELAXED, __HIP_MEMORY_SCOPE_AGENT);
            if (kn != 0 && kn != ENC_MIN_ID)
                __hip_atomic_fetch_max(&mink[col], kn,
                                       __ATOMIC_RELAXED, __HIP_MEMORY_SCOPE_AGENT);
        }
    } else {
        // ---------------- cross-entropy ----------------
        int R0 = (bid - NTILE) * 16;
        lg[tid >> 4][112 + (tid & 15)] = -INFINITY;   // pad cols 112..127

        int arow = R0 + lm;
        const unsigned short* apt = ebf + arow * DIM + koff;
        short8 a0 = *reinterpret_cast<const short8*>(apt);
        short8 a1 = *reinterpret_cast<const short8*>(apt + 32);
        short8 a2 = *reinterpret_cast<const short8*>(apt + 64);
        short8 a3 = *reinterpret_cast<const short8*>(apt + 96);

        for (int t = wave * 2; t < 7 && t < wave * 2 + 2; ++t) {
            int cls = t * 16 + lm;
            const unsigned short* bp = wbf + cls * DIM + koff;
            short8 b0 = *reinterpret_cast<const short8*>(bp);
            short8 b1 = *reinterpret_cast<const short8*>(bp + 32);
            short8 b2 = *reinterpret_cast<const short8*>(bp + 64);
            short8 b3 = *reinterpret_cast<const short8*>(bp + 96);
            f32x4 c = {0.f, 0.f, 0.f, 0.f};
            c = __builtin_amdgcn_mfma_f32_16x16x32_bf16(a0, b0, c, 0, 0, 0);
            c = __builtin_amdgcn_mfma_f32_16x16x32_bf16(a1, b1, c, 0, 0, 0);
            c = __builtin_amdgcn_mfma_f32_16x16x32_bf16(a2, b2, c, 0, 0, 0);
            c = __builtin_amdgcn_mfma_f32_16x16x32_bf16(a3, b3, c, 0, 0, 0);
            float bias = (cls < NCLS) ? fcb[cls] : -INFINITY;
            #pragma unroll
            for (int r = 0; r < 4; ++r)
                lg[lq * 4 + r][t * 16 + lm] = c[r] + bias;
        }
        __syncthreads();
        float cacc = 0.f;
        #pragma unroll
        for (int i = 0; i < 4; ++i) {
            int r = wave * 4 + i;
            float x0 = lg[r][lane], x1 = lg[r][lane + 64];
            float m = fmaxf(x0, x1);
            #pragma unroll
            for (int off = 1; off < 64; off <<= 1) m = fmaxf(m, __shfl_xor(m, off, 64));
            float s = expf(x0 - m) + expf(x1 - m);    // -inf pads -> 0
            #pragma unroll
            for (int off = 1; off < 64; off <<= 1) s += __shfl_xor(s, off, 64);
            if (lane == 0) {
                int lab = labels[R0 + r];
                cacc += (m + logf(s)) - lg[r][lab];
            }
        }
        __syncthreads();
        if (lane == 0) lg[0][wave] = cacc;
        __syncthreads();
        if (tid == 0) {
            float bsum = lg[0][0] + lg[0][1] + lg[0][2] + lg[0][3];
            __hip_atomic_fetch_add(ce_sum, bsum,
                                   __ATOMIC_RELAXED, __HIP_MEMORY_SCOPE_AGENT);
        }
    }

    // ------- fence-free ticket fan-in -------
    __syncthreads();
    asm volatile("s_waitcnt vmcnt(0)" ::: "memory");
    if (tid == 0) {
        int old = __hip_atomic_fetch_add(ticket, 1,
                                         __ATOMIC_RELAXED, __HIP_MEMORY_SCOPE_AGENT);
        lastFlag = (old == GRID_MAIN - 1);
    }
    __syncthreads();
    if (lastFlag) {
        float acc = 0.f;
        #pragma unroll
        for (int rr = 0; rr < 16; ++rr) {
            int row = rr * 256 + tid;
            unsigned int kx = __hip_atomic_load(&maxk[row], __ATOMIC_RELAXED,
                                                __HIP_MEMORY_SCOPE_AGENT);
            unsigned int kn = __hip_atomic_load(&mink[row], __ATOMIC_RELAXED,
                                                __HIP_MEMORY_SCOPE_AGENT);
            float ap = sqrtf(fmaxf(dec_max(kx), 1e-12f));
            float an = sqrtf(fmaxf(dec_min(kn), 1e-12f));
            acc += fmaxf(ap - an + MARGIN, 0.f);
        }
        float* red = reinterpret_cast<float*>(lg);
        red[tid] = acc;
        __syncthreads();
        for (int s = 128; s > 0; s >>= 1) {
            if (tid < s) red[tid] += red[tid + s];
            __syncthreads();
        }
        if (tid == 0) {
            float ces = __hip_atomic_load(ce_sum, __ATOMIC_RELAXED,
                                          __HIP_MEMORY_SCOPE_AGENT);
            out[0] = (red[0] + ces) * (1.0f / BATCH);
        }
    }
}

extern "C" void kernel_launch(void* const* d_in, const int* in_sizes, int n_in,
                              void* d_out, int out_size, void* d_ws, size_t ws_size,
                              hipStream_t stream) {
    const float* emb    = (const float*)d_in[0];
    const int*   labels = (const int*)  d_in[1];
    const float* fcw    = (const float*)d_in[2];
    const float* fcb    = (const float*)d_in[3];
    float* out = (float*)d_out;

    char* ws = (char*)d_ws;
    unsigned short* ebf = (unsigned short*)(ws);                 // 1 MB
    unsigned short* wbf = (unsigned short*)(ws + 1048576);       // 28 KB (pad 32K)
    float* sq           = (float*)(ws + 1081344);                // 16 KB
    char* fan           = ws + 1097728;                          // zeroed by prep
    int*   ticket       = (int*)(fan);                           // 4 B
    float* ce_sum       = (float*)(fan + 4);                     // 4 B
    unsigned int* maxk  = (unsigned int*)(fan + 8);              // 16 KB
    unsigned int* mink  = (unsigned int*)(fan + 8 + 16384);      // 16 KB

    prep_kernel<<<258, 256, 0, stream>>>(emb, fcw, ebf, sq, wbf,
                                         (unsigned int*)fan);
    main_kernel<<<GRID_MAIN, 256, 0, stream>>>(ebf, wbf, sq, labels, fcb,
                                               maxk, mink, ce_sum, ticket, out);
}